// Round 5
// baseline (211.555 us; speedup 1.0000x reference)
//
#include <hip/hip_runtime.h>
#include <hip/hip_bf16.h>

typedef __bf16 bf16x8_t __attribute__((ext_vector_type(8)));
typedef float f32x4_t __attribute__((ext_vector_type(4)));

#define MFMA_BF16(a, b, c) __builtin_amdgcn_mfma_f32_16x16x32_bf16((a), (b), (c), 0, 0, 0)
#define SCHED_PIN() __builtin_amdgcn_sched_barrier(0)
// Raw barrier: LDS-visibility only; deliberately NO vmcnt drain so prefetch
// global loads stay in flight across the barrier.
#define LGKM0_BARRIER() do { \
    asm volatile("s_waitcnt lgkmcnt(0)" ::: "memory"); \
    __builtin_amdgcn_s_barrier(); } while (0)

static constexpr int T_DIM = 512;
static constexpr int H_DIM = 7168;
static constexpr int F_DIM = 2048;

__device__ __forceinline__ ushort f2bf(float f) {
    return __builtin_bit_cast(ushort, __float2bfloat16(f));
}

// XOR-swizzle for [rows][64-ushort] LDS tiles, 16B-unit granularity.
__device__ __forceinline__ int swzu(int row, int c16) {
    return (row << 6) + (((c16) ^ (row & 7)) << 3);
}
// 8B-granular variant for staging writes (c8 in [0,16))
__device__ __forceinline__ int swz8(int row, int c8) {
    return (row << 6) + ((((c8 >> 1) ^ (row & 7))) << 3) + ((c8 & 1) << 2);
}

__global__ void cvt_x_kernel(const float* __restrict__ in, ushort* __restrict__ outp, int n4) {
    int i = blockIdx.x * 256 + threadIdx.x;
    if (i < n4) {
        float4 v = reinterpret_cast<const float4*>(in)[i];
        ushort4 o;
        o.x = f2bf(v.x); o.y = f2bf(v.y); o.z = f2bf(v.z); o.w = f2bf(v.w);
        reinterpret_cast<ushort4*>(outp)[i] = o;
    }
}

// ---------------- gate+up fused GEMM, combined N=4096, split-K ----------------
// BM=128, BN=128, BK=64. 512 thr = 8 waves (2m x 4n), wave tile 64x32.
// 2-deep pinned register prefetch + double-buffered LDS + raw barriers
// (no vmcnt drain). STORE's vmcnt is compiler-counted against loads issued
// ~1.5 iterations earlier.
__global__ __launch_bounds__(512, 4) void gate_up_kernel(
    const ushort* __restrict__ xb, const float* __restrict__ wg,
    const float* __restrict__ sg, const float* __restrict__ wu,
    const float* __restrict__ su, float* __restrict__ gp, int NTS)
{
    __shared__ ushort As[2][128 * 64];
    __shared__ ushort Bs[2][128 * 64];

    const int tid = threadIdx.x;
    const int lane = tid & 63;
    const int wid = tid >> 6;
    const int wr = wid >> 2, wcn = wid & 3;   // wave 64x32 tile at (wr*64, wcn*32)
    const int bn = blockIdx.x, bm = blockIdx.y, bz = blockIdx.z;
    const int m0 = bm * 128;
    const int ks0 = bz * NTS, ks1 = ks0 + NTS;

    const float* __restrict__ Wb = (bn < 16) ? wg : wu;
    const float* __restrict__ srow = ((bn < 16) ? sg : su) + (size_t)(bn & 15) * (H_DIM / 128);
    const int nb = (bn & 15) * 128;

    const int ar = tid >> 3, au = tid & 7;
    const int br = tid >> 4, bf4 = tid & 15;

    uint4 ra[2][2];
    float4 rb[2][4];
    f32x4_t acc[4][2] = {};

    auto LOADG = [&](int kt, int s) {
        const int k0 = kt * 64;
        #pragma unroll
        for (int q = 0; q < 2; ++q)
            ra[s][q] = *reinterpret_cast<const uint4*>(
                &xb[(size_t)(m0 + q * 64 + ar) * H_DIM + k0 + au * 8]);
        #pragma unroll
        for (int p = 0; p < 4; ++p)
            rb[s][p] = *reinterpret_cast<const float4*>(
                &Wb[(size_t)(nb + p * 32 + br) * H_DIM + k0 + bf4 * 4]);
    };

    auto STORE = [&](int kt, int s, int b) {
        const float sc = srow[kt >> 1];
        #pragma unroll
        for (int q = 0; q < 2; ++q)
            *reinterpret_cast<uint4*>(&As[b][swzu(q * 64 + ar, au)]) = ra[s][q];
        #pragma unroll
        for (int p = 0; p < 4; ++p) {
            const int row = p * 32 + br;
            ushort4 w4;
            w4.x = f2bf(rb[s][p].x * sc); w4.y = f2bf(rb[s][p].y * sc);
            w4.z = f2bf(rb[s][p].z * sc); w4.w = f2bf(rb[s][p].w * sc);
            *reinterpret_cast<ushort4*>(&Bs[b][swz8(row, bf4)]) = w4;
        }
    };

    auto COMPUTE = [&](int b) {
        #pragma unroll
        for (int ks = 0; ks < 2; ++ks) {
            const int ku = ks * 4 + (lane >> 4);
            bf16x8_t af[4], bf[2];
            #pragma unroll
            for (int i = 0; i < 4; ++i)
                af[i] = *reinterpret_cast<const bf16x8_t*>(
                    &As[b][swzu(wr * 64 + i * 16 + (lane & 15), ku)]);
            #pragma unroll
            for (int j = 0; j < 2; ++j)
                bf[j] = *reinterpret_cast<const bf16x8_t*>(
                    &Bs[b][swzu(wcn * 32 + j * 16 + (lane & 15), ku)]);
            #pragma unroll
            for (int i = 0; i < 4; ++i)
                #pragma unroll
                for (int j = 0; j < 2; ++j)
                    acc[i][j] = MFMA_BF16(af[i], bf[j], acc[i][j]);
        }
    };

    // Prologue: sets 0,1 in flight; tile ks0 staged to LDS buf0.
    LOADG(ks0, 0);
    LOADG(ks0 + 1, 1);
    STORE(ks0, 0, 0);       // counted vmcnt: waits set0 only, set1 stays in flight
    LGKM0_BARRIER();

    for (int kt = ks0; kt < ks1; kt += 2) {
        if (kt + 2 < ks1) LOADG(kt + 2, 0);
        SCHED_PIN();        // loads stay above; compute below
        COMPUTE(0);
        STORE(kt + 1, 1, 1);
        LGKM0_BARRIER();

        if (kt + 3 < ks1) LOADG(kt + 3, 1);
        SCHED_PIN();
        COMPUTE(1);
        if (kt + 2 < ks1) {
            STORE(kt + 2, 0, 0);
            LGKM0_BARRIER();
        }
    }

    // fp32 partials: P[bz][T][4096]
    #pragma unroll
    for (int i = 0; i < 4; ++i)
        #pragma unroll
        for (int j = 0; j < 2; ++j)
            #pragma unroll
            for (int r = 0; r < 4; ++r) {
                const int m = m0 + wr * 64 + i * 16 + (lane >> 4) * 4 + r;
                const int nc = bn * 128 + wcn * 32 + j * 16 + (lane & 15);
                gp[(size_t)bz * T_DIM * 4096 + (size_t)m * 4096 + nc] = acc[i][j][r];
            }
}

// reduce split-K partials: h = silu(sum g) * (sum u), bf16. P cols [0,2048)=g, [2048,4096)=u
__global__ void h_reduce_kernel(const float* __restrict__ gp, ushort* __restrict__ hb,
                                int nsplit, int n4) {
    int i = blockIdx.x * 256 + threadIdx.x;
    if (i >= n4) return;
    const int m = i >> 9;
    const int c4 = i & 511;
    const size_t base = (size_t)m * 4096 + c4 * 4;
    const size_t stride = (size_t)T_DIM * 4096;
    float4 g = *reinterpret_cast<const float4*>(&gp[base]);
    float4 u = *reinterpret_cast<const float4*>(&gp[base + 2048]);
    for (int s = 1; s < nsplit; ++s) {
        float4 g2 = *reinterpret_cast<const float4*>(&gp[s * stride + base]);
        float4 u2 = *reinterpret_cast<const float4*>(&gp[s * stride + base + 2048]);
        g.x += g2.x; g.y += g2.y; g.z += g2.z; g.w += g2.w;
        u.x += u2.x; u.y += u2.y; u.z += u2.z; u.w += u2.w;
    }
    ushort4 o;
    o.x = f2bf(g.x / (1.0f + __expf(-g.x)) * u.x);
    o.y = f2bf(g.y / (1.0f + __expf(-g.y)) * u.y);
    o.z = f2bf(g.z / (1.0f + __expf(-g.z)) * u.z);
    o.w = f2bf(g.w / (1.0f + __expf(-g.w)) * u.w);
    reinterpret_cast<ushort4*>(hb)[i] = o;
}

// ---------------- down GEMM ----------------
// BM=128, BN=128, BK=64, K=2048. Grid (56, 4). Same pinned 2-deep pipeline.
__global__ __launch_bounds__(512, 4) void down_kernel(
    const ushort* __restrict__ hb, const float* __restrict__ wd,
    const float* __restrict__ sd, float* __restrict__ out)
{
    __shared__ ushort As[2][128 * 64];
    __shared__ ushort Bs[2][128 * 64];

    const int tid = threadIdx.x;
    const int lane = tid & 63;
    const int wid = tid >> 6;
    const int wr = wid >> 2, wcn = wid & 3;
    const int bn = blockIdx.x, bm = blockIdx.y;
    const int m0 = bm * 128;
    const float* __restrict__ srow = sd + (size_t)bn * (F_DIM / 128);
    const int nb = bn * 128;
    const int NT = F_DIM / 64;  // 32

    const int ar = tid >> 3, au = tid & 7;
    const int br = tid >> 4, bf4 = tid & 15;

    uint4 ra[2][2];
    float4 rb[2][4];
    f32x4_t acc[4][2] = {};

    auto LOADG = [&](int kt, int s) {
        const int k0 = kt * 64;
        #pragma unroll
        for (int q = 0; q < 2; ++q)
            ra[s][q] = *reinterpret_cast<const uint4*>(
                &hb[(size_t)(m0 + q * 64 + ar) * F_DIM + k0 + au * 8]);
        #pragma unroll
        for (int p = 0; p < 4; ++p)
            rb[s][p] = *reinterpret_cast<const float4*>(
                &wd[(size_t)(nb + p * 32 + br) * F_DIM + k0 + bf4 * 4]);
    };

    auto STORE = [&](int kt, int s, int b) {
        const float sc = srow[kt >> 1];
        #pragma unroll
        for (int q = 0; q < 2; ++q)
            *reinterpret_cast<uint4*>(&As[b][swzu(q * 64 + ar, au)]) = ra[s][q];
        #pragma unroll
        for (int p = 0; p < 4; ++p) {
            const int row = p * 32 + br;
            ushort4 w4;
            w4.x = f2bf(rb[s][p].x * sc); w4.y = f2bf(rb[s][p].y * sc);
            w4.z = f2bf(rb[s][p].z * sc); w4.w = f2bf(rb[s][p].w * sc);
            *reinterpret_cast<ushort4*>(&Bs[b][swz8(row, bf4)]) = w4;
        }
    };

    auto COMPUTE = [&](int b) {
        #pragma unroll
        for (int ks = 0; ks < 2; ++ks) {
            const int ku = ks * 4 + (lane >> 4);
            bf16x8_t af[4], bf[2];
            #pragma unroll
            for (int i = 0; i < 4; ++i)
                af[i] = *reinterpret_cast<const bf16x8_t*>(
                    &As[b][swzu(wr * 64 + i * 16 + (lane & 15), ku)]);
            #pragma unroll
            for (int j = 0; j < 2; ++j)
                bf[j] = *reinterpret_cast<const bf16x8_t*>(
                    &Bs[b][swzu(wcn * 32 + j * 16 + (lane & 15), ku)]);
            #pragma unroll
            for (int i = 0; i < 4; ++i)
                #pragma unroll
                for (int j = 0; j < 2; ++j)
                    acc[i][j] = MFMA_BF16(af[i], bf[j], acc[i][j]);
        }
    };

    LOADG(0, 0);
    LOADG(1, 1);
    STORE(0, 0, 0);
    LGKM0_BARRIER();

    for (int kt = 0; kt < NT; kt += 2) {
        if (kt + 2 < NT) LOADG(kt + 2, 0);
        SCHED_PIN();
        COMPUTE(0);
        STORE(kt + 1, 1, 1);
        LGKM0_BARRIER();

        if (kt + 3 < NT) LOADG(kt + 3, 1);
        SCHED_PIN();
        COMPUTE(1);
        if (kt + 2 < NT) {
            STORE(kt + 2, 0, 0);
            LGKM0_BARRIER();
        }
    }

    #pragma unroll
    for (int i = 0; i < 4; ++i)
        #pragma unroll
        for (int j = 0; j < 2; ++j)
            #pragma unroll
            for (int r = 0; r < 4; ++r) {
                const int m = m0 + wr * 64 + i * 16 + (lane >> 4) * 4 + r;
                const int nc = nb + wcn * 32 + j * 16 + (lane & 15);
                out[(size_t)m * H_DIM + nc] = acc[i][j][r];
            }
}

extern "C" void kernel_launch(void* const* d_in, const int* in_sizes, int n_in,
                              void* d_out, int out_size, void* d_ws, size_t ws_size,
                              hipStream_t stream) {
    const float* x  = (const float*)d_in[0];
    const float* wg = (const float*)d_in[1];
    const float* sg = (const float*)d_in[2];
    const float* wu = (const float*)d_in[3];
    const float* su = (const float*)d_in[4];
    const float* wd = (const float*)d_in[5];
    const float* sd = (const float*)d_in[6];
    float* out = (float*)d_out;

    ushort* xb = (ushort*)d_ws;                       // 7.34 MB
    ushort* hb = xb + (size_t)T_DIM * H_DIM;          // 2.10 MB
    float*  gp = (float*)(hb + (size_t)T_DIM * F_DIM);

    const size_t base_b = (size_t)T_DIM * H_DIM * 2 + (size_t)T_DIM * F_DIM * 2;
    const size_t split_b = (size_t)T_DIM * 4096 * 4;  // combined g|u fp32 per split

    int nsplit = 1;
    if (ws_size >= base_b + 4 * split_b) nsplit = 4;
    else if (ws_size >= base_b + 2 * split_b) nsplit = 2;

    const int n4x = T_DIM * H_DIM / 4;
    cvt_x_kernel<<<n4x / 256, 256, 0, stream>>>(x, xb, n4x);

    gate_up_kernel<<<dim3(32, T_DIM / 128, nsplit), 512, 0, stream>>>(
        xb, wg, sg, wu, su, gp, (H_DIM / 64) / nsplit);

    const int n4h = T_DIM * F_DIM / 4;
    h_reduce_kernel<<<n4h / 256, 256, 0, stream>>>(gp, hb, nsplit, n4h);

    down_kernel<<<dim3(H_DIM / 128, T_DIM / 128), 512, 0, stream>>>(hb, wd, sd, out);
}

// Round 6
// 123.758 us; speedup vs baseline: 1.7094x; 1.7094x over previous
//
#include <hip/hip_runtime.h>
#include <hip/hip_bf16.h>

typedef __bf16 bf16x8_t __attribute__((ext_vector_type(8)));
typedef float f32x4_t __attribute__((ext_vector_type(4)));

#define MFMA_BF16(a, b, c) __builtin_amdgcn_mfma_f32_16x16x32_bf16((a), (b), (c), 0, 0, 0)

static constexpr int T_DIM = 512;
static constexpr int H_DIM = 7168;
static constexpr int F_DIM = 2048;

__device__ __forceinline__ ushort f2bf(float f) {
    return __builtin_bit_cast(ushort, __float2bfloat16(f));
}

// Async global->LDS, 16B per lane. Dest must be uniform_base + lane*16 (HW rule).
__device__ __forceinline__ void gload_lds16(const void* g, void* l) {
    __builtin_amdgcn_global_load_lds(
        (const __attribute__((address_space(1))) unsigned int*)g,
        (__attribute__((address_space(3))) unsigned int*)(uintptr_t)l,
        16, 0, 0);
}

__global__ void cvt_x_kernel(const float* __restrict__ in, ushort* __restrict__ outp, int n4) {
    int i = blockIdx.x * 256 + threadIdx.x;
    if (i < n4) {
        float4 v = reinterpret_cast<const float4*>(in)[i];
        ushort4 o;
        o.x = f2bf(v.x); o.y = f2bf(v.y); o.z = f2bf(v.z); o.w = f2bf(v.w);
        reinterpret_cast<ushort4*>(outp)[i] = o;
    }
}

// ---------------- gate+up fused GEMM, combined N=4096, split-K ----------------
// BM=128, BN=128, BK=64. 256 thr = 4 waves (2x2), wave tile 64x64.
// m97 structure: global_load_lds staging (A bf16, B raw fp32), single-buffer
// LDS 48KB, 2 barriers/tile. Dequant at consumer (1 scalar/tile).
// LDS layouts XOR-swizzled via pre-swizzled GLOBAL source + swizzled read.
__global__ __launch_bounds__(256) void gate_up_kernel(
    const ushort* __restrict__ xb, const float* __restrict__ wg,
    const float* __restrict__ sg, const float* __restrict__ wu,
    const float* __restrict__ su, float* __restrict__ gp, int NTS)
{
    __shared__ ushort As[128 * 64];   // bf16, 16KB, swz: c16u ^= row&7
    __shared__ float  Bs[128 * 64];   // fp32, 32KB, swz: c32u ^= row&7

    const int tid = threadIdx.x;
    const int lane = tid & 63;
    const int wid = tid >> 6;
    const int wr = wid >> 1, wc = wid & 1;
    const int bn = blockIdx.x, bm = blockIdx.y, bz = blockIdx.z;
    const int m0 = bm * 128;
    const int ks0 = bz * NTS, ks1 = ks0 + NTS;

    const float* __restrict__ Wb = (bn < 16) ? wg : wu;
    const float* __restrict__ srow = ((bn < 16) ? sg : su) + (size_t)(bn & 15) * (H_DIM / 128);
    const int nb = (bn & 15) * 128;

    f32x4_t acc[4][4] = {};

    // A: 4 chunks/thread; chunk q -> LDS byte q*4096 + tid*16 (= wave-uniform + lane*16)
    const int a_row_lo = tid >> 3, a_cu = tid & 7;
    // B: 8 chunks/thread; fp32 rows of 256B = 8x 32B units
    const int b_row_lo = tid >> 4, b_c32 = (tid & 15) >> 1, b_half = tid & 1;

    auto STAGE = [&](int kt) {
        const int k0 = kt * 64;
        #pragma unroll
        for (int q = 0; q < 4; ++q) {
            const int row = q * 32 + a_row_lo;
            gload_lds16(&xb[(size_t)(m0 + row) * H_DIM + k0 + ((a_cu ^ (row & 7)) << 3)],
                        &As[(q * 4096 + tid * 16) >> 1]);
        }
        #pragma unroll
        for (int q = 0; q < 8; ++q) {
            const int row = q * 16 + b_row_lo;
            gload_lds16(&Wb[(size_t)(nb + row) * H_DIM + k0 + ((b_c32 ^ (row & 7)) << 3) + (b_half << 2)],
                        &Bs[(q * 4096 + tid * 16) >> 2]);
        }
    };

    auto COMPUTE = [&](int kt) {
        const float s = srow[kt >> 1];
        #pragma unroll
        for (int ks = 0; ks < 2; ++ks) {
            const int kk = ks * 4 + (lane >> 4);
            bf16x8_t af[4];
            #pragma unroll
            for (int i = 0; i < 4; ++i) {
                const int row = wr * 64 + i * 16 + (lane & 15);
                af[i] = *reinterpret_cast<const bf16x8_t*>(&As[row * 64 + ((kk ^ (row & 7)) << 3)]);
            }
            #pragma unroll
            for (int j = 0; j < 4; ++j) {
                const int row = wc * 64 + j * 16 + (lane & 15);
                const int u32 = kk ^ (row & 7);
                f32x4_t b0 = *reinterpret_cast<const f32x4_t*>(&Bs[row * 64 + u32 * 8]);
                f32x4_t b1 = *reinterpret_cast<const f32x4_t*>(&Bs[row * 64 + u32 * 8 + 4]);
                bf16x8_t bf;
                #pragma unroll
                for (int e = 0; e < 4; ++e) {
                    bf[e]     = (__bf16)(b0[e] * s);
                    bf[e + 4] = (__bf16)(b1[e] * s);
                }
                #pragma unroll
                for (int i = 0; i < 4; ++i)
                    acc[i][j] = MFMA_BF16(af[i], bf, acc[i][j]);
            }
        }
    };

    STAGE(ks0);
    __syncthreads();                 // vmcnt drained -> tile ready
    for (int kt = ks0; kt < ks1; ++kt) {
        COMPUTE(kt);
        if (kt + 1 < ks1) {
            __syncthreads();         // all waves done reading
            STAGE(kt + 1);
            __syncthreads();         // vmcnt drained
        }
    }

    // fp32 partials: P[bz][T][4096]
    #pragma unroll
    for (int i = 0; i < 4; ++i)
        #pragma unroll
        for (int j = 0; j < 4; ++j)
            #pragma unroll
            for (int r = 0; r < 4; ++r) {
                const int m = m0 + wr * 64 + i * 16 + (lane >> 4) * 4 + r;
                const int nc = bn * 128 + wc * 64 + j * 16 + (lane & 15);
                gp[(size_t)bz * T_DIM * 4096 + (size_t)m * 4096 + nc] = acc[i][j][r];
            }
}

// reduce split-K partials: h = silu(sum g) * (sum u), bf16. P cols [0,2048)=g, [2048,4096)=u
__global__ void h_reduce_kernel(const float* __restrict__ gp, ushort* __restrict__ hb,
                                int nsplit, int n4) {
    int i = blockIdx.x * 256 + threadIdx.x;
    if (i >= n4) return;
    const int m = i >> 9;
    const int c4 = i & 511;
    const size_t base = (size_t)m * 4096 + c4 * 4;
    const size_t stride = (size_t)T_DIM * 4096;
    float4 g = *reinterpret_cast<const float4*>(&gp[base]);
    float4 u = *reinterpret_cast<const float4*>(&gp[base + 2048]);
    for (int s = 1; s < nsplit; ++s) {
        float4 g2 = *reinterpret_cast<const float4*>(&gp[s * stride + base]);
        float4 u2 = *reinterpret_cast<const float4*>(&gp[s * stride + base + 2048]);
        g.x += g2.x; g.y += g2.y; g.z += g2.z; g.w += g2.w;
        u.x += u2.x; u.y += u2.y; u.z += u2.z; u.w += u2.w;
    }
    ushort4 o;
    o.x = f2bf(g.x / (1.0f + __expf(-g.x)) * u.x);
    o.y = f2bf(g.y / (1.0f + __expf(-g.y)) * u.y);
    o.z = f2bf(g.z / (1.0f + __expf(-g.z)) * u.z);
    o.w = f2bf(g.w / (1.0f + __expf(-g.w)) * u.w);
    reinterpret_cast<ushort4*>(hb)[i] = o;
}

// ---------------- down GEMM ----------------
// BM=64, BN=128, BK=64, K=2048. Grid (56, 8) = 448 blocks. Same m97 structure.
// 4 waves 2x2, wave tile 32x64. LDS 40KB -> 4 blocks/CU capacity.
__global__ __launch_bounds__(256) void down_kernel(
    const ushort* __restrict__ hb, const float* __restrict__ wd,
    const float* __restrict__ sd, float* __restrict__ out)
{
    __shared__ ushort As[64 * 64];    // 8KB
    __shared__ float  Bs[128 * 64];   // 32KB

    const int tid = threadIdx.x;
    const int lane = tid & 63;
    const int wid = tid >> 6;
    const int wr = wid >> 1, wc = wid & 1;
    const int bn = blockIdx.x, bm = blockIdx.y;
    const int m0 = bm * 64;
    const float* __restrict__ srow = sd + (size_t)bn * (F_DIM / 128);
    const int nb = bn * 128;
    const int NT = F_DIM / 64;  // 32

    f32x4_t acc[2][4] = {};

    const int a_row_lo = tid >> 3, a_cu = tid & 7;
    const int b_row_lo = tid >> 4, b_c32 = (tid & 15) >> 1, b_half = tid & 1;

    auto STAGE = [&](int kt) {
        const int k0 = kt * 64;
        #pragma unroll
        for (int q = 0; q < 2; ++q) {
            const int row = q * 32 + a_row_lo;
            gload_lds16(&hb[(size_t)(m0 + row) * F_DIM + k0 + ((a_cu ^ (row & 7)) << 3)],
                        &As[(q * 4096 + tid * 16) >> 1]);
        }
        #pragma unroll
        for (int q = 0; q < 8; ++q) {
            const int row = q * 16 + b_row_lo;
            gload_lds16(&wd[(size_t)(nb + row) * F_DIM + k0 + ((b_c32 ^ (row & 7)) << 3) + (b_half << 2)],
                        &Bs[(q * 4096 + tid * 16) >> 2]);
        }
    };

    auto COMPUTE = [&](int kt) {
        const float s = srow[kt >> 1];
        #pragma unroll
        for (int ks = 0; ks < 2; ++ks) {
            const int kk = ks * 4 + (lane >> 4);
            bf16x8_t af[2];
            #pragma unroll
            for (int i = 0; i < 2; ++i) {
                const int row = wr * 32 + i * 16 + (lane & 15);
                af[i] = *reinterpret_cast<const bf16x8_t*>(&As[row * 64 + ((kk ^ (row & 7)) << 3)]);
            }
            #pragma unroll
            for (int j = 0; j < 4; ++j) {
                const int row = wc * 64 + j * 16 + (lane & 15);
                const int u32 = kk ^ (row & 7);
                f32x4_t b0 = *reinterpret_cast<const f32x4_t*>(&Bs[row * 64 + u32 * 8]);
                f32x4_t b1 = *reinterpret_cast<const f32x4_t*>(&Bs[row * 64 + u32 * 8 + 4]);
                bf16x8_t bf;
                #pragma unroll
                for (int e = 0; e < 4; ++e) {
                    bf[e]     = (__bf16)(b0[e] * s);
                    bf[e + 4] = (__bf16)(b1[e] * s);
                }
                #pragma unroll
                for (int i = 0; i < 2; ++i)
                    acc[i][j] = MFMA_BF16(af[i], bf, acc[i][j]);
            }
        }
    };

    STAGE(0);
    __syncthreads();
    for (int kt = 0; kt < NT; ++kt) {
        COMPUTE(kt);
        if (kt + 1 < NT) {
            __syncthreads();
            STAGE(kt + 1);
            __syncthreads();
        }
    }

    #pragma unroll
    for (int i = 0; i < 2; ++i)
        #pragma unroll
        for (int j = 0; j < 4; ++j)
            #pragma unroll
            for (int r = 0; r < 4; ++r) {
                const int m = m0 + wr * 32 + i * 16 + (lane >> 4) * 4 + r;
                const int nc = nb + wc * 64 + j * 16 + (lane & 15);
                out[(size_t)m * H_DIM + nc] = acc[i][j][r];
            }
}

extern "C" void kernel_launch(void* const* d_in, const int* in_sizes, int n_in,
                              void* d_out, int out_size, void* d_ws, size_t ws_size,
                              hipStream_t stream) {
    const float* x  = (const float*)d_in[0];
    const float* wg = (const float*)d_in[1];
    const float* sg = (const float*)d_in[2];
    const float* wu = (const float*)d_in[3];
    const float* su = (const float*)d_in[4];
    const float* wd = (const float*)d_in[5];
    const float* sd = (const float*)d_in[6];
    float* out = (float*)d_out;

    ushort* xb = (ushort*)d_ws;                       // 7.34 MB
    ushort* hb = xb + (size_t)T_DIM * H_DIM;          // 2.10 MB
    float*  gp = (float*)(hb + (size_t)T_DIM * F_DIM);

    const size_t base_b = (size_t)T_DIM * H_DIM * 2 + (size_t)T_DIM * F_DIM * 2;
    const size_t split_b = (size_t)T_DIM * 4096 * 4;  // combined g|u fp32 per split

    int nsplit = 1;
    if (ws_size >= base_b + 4 * split_b) nsplit = 4;
    else if (ws_size >= base_b + 2 * split_b) nsplit = 2;

    const int n4x = T_DIM * H_DIM / 4;
    cvt_x_kernel<<<n4x / 256, 256, 0, stream>>>(x, xb, n4x);

    gate_up_kernel<<<dim3(32, T_DIM / 128, nsplit), 256, 0, stream>>>(
        xb, wg, sg, wu, su, gp, (H_DIM / 64) / nsplit);

    const int n4h = T_DIM * F_DIM / 4;
    h_reduce_kernel<<<n4h / 256, 256, 0, stream>>>(gp, hb, nsplit, n4h);

    down_kernel<<<dim3(H_DIM / 128, T_DIM / 64), 256, 0, stream>>>(hb, wd, sd, out);
}